// Round 1
// baseline (68.244 us; speedup 1.0000x reference)
//
#include <hip/hip_runtime.h>

// one_layer_net: 130-step scan over a 9x3 LUT-triangle network.
// State lives in lanes 0..26 of wave 0 (lane = t*3+j); lanes 27/28 hold the
// two network inputs a=x[0], b=x[1] so the reference's flat[29] gather is a
// single cross-lane shuffle. Per-step noisy-weight coefficients are
// precomputed in parallel into LDS (they don't depend on state), leaving the
// serial loop with: 1 ds_read_b128 + 2 ds_bpermute + short fma chain.

#define STEPS 130
#define NLUT  27   // 9 triangles x 3 LUTs

// Source wiring (indices into flat[29] = [prev.flatten(27), a, b])
__device__ __constant__ int c_idx0[9] = {3, 0, 6, 12, 9, 15, 18, 6, 15};
__device__ __constant__ int c_idx1[9] = {1, 7, 4, 19, 16, 13, 10, 22, 25};
__device__ __constant__ int c_idx2[9] = {17, 5, 11, 8, 28, 2, 27, 23, 26};

__global__ __launch_bounds__(1024)
void one_layer_net_kernel(const float* __restrict__ x,
                          const float* __restrict__ weights,
                          const float* __restrict__ noise,
                          float* __restrict__ out) {
    // Per-step mux coefficients: m = fma(sel, hd, hs). Layout [step][lut].
    __shared__ float4 tbl[STEPS * NLUT];   // 130*27*16 = 56160 B LDS

    const int tid = threadIdx.x;

    // ---- Phase 1: parallel precompute of noisy-weight coefficients ----
    // w' = w + |1 - |w|| * n * 0.125
    // mux(s, w0', w1') = fma(s, 0.5*(w1'-w0'), 0.5*(w0'+w1'))
    const float4* __restrict__ w4 = (const float4*)weights; // [27]
    const float4* __restrict__ n4 = (const float4*)noise;   // [130*27]
    for (int i = tid; i < STEPS * NLUT; i += 1024) {
        const int l = i % NLUT;
        float4 w = w4[l];
        float4 n = n4[i];
        float w0 = fmaf(fabsf(1.0f - fabsf(w.x)) * n.x, 0.125f, w.x);
        float w1 = fmaf(fabsf(1.0f - fabsf(w.y)) * n.y, 0.125f, w.y);
        float w2 = fmaf(fabsf(1.0f - fabsf(w.z)) * n.z, 0.125f, w.z);
        float w3 = fmaf(fabsf(1.0f - fabsf(w.w)) * n.w, 0.125f, w.w);
        tbl[i] = make_float4(0.5f * (w1 - w0), 0.5f * (w0 + w1),
                             0.5f * (w3 - w2), 0.5f * (w2 + w3));
    }
    __syncthreads();

    // ---- Phase 2: serial 130-step loop on wave 0 only ----
    if (tid >= 64) return;

    const int l  = tid;
    const int lc = (l < NLUT) ? l : (NLUT - 1); // clamp for lanes 27..63
    const int t  = lc / 3;
    const int j  = lc % 3;
    // LUT0(x1,x2): selA=x1 selB=x2 | LUT1(x0,x2): selA=x0 selB=x2
    // LUT2(x0,x1): selA=x0 selB=x1
    const int srcA = (j == 0) ? c_idx1[t] : c_idx0[t];
    const int srcB = (j == 2) ? c_idx1[t] : c_idx2[t];

    // lanes 0..26: state (init -1); lane 27: a=x[0]; lane 28: b=x[1]
    float state = (l < NLUT) ? -1.0f
                : (l == 27)  ? x[0]
                : (l == 28)  ? x[1]
                : 0.0f;

    const float4* __restrict__ row = &tbl[lc];
    #pragma unroll 2
    for (int s = 0; s < STEPS; ++s) {
        float4 nf = row[s * NLUT];                 // address independent of state
        float gA = __shfl(state, srcA, 64);
        float gB = __shfl(state, srcB, 64);
        float m0 = fmaf(gA, nf.x, nf.y);
        float m1 = fmaf(gA, nf.z, nf.w);
        float nw = 0.5f * fmaf(gB, m1 - m0, m0 + m1);
        state = (l < NLUT) ? nw : state;           // lanes 27/28 keep x
    }

    // outputs: final[0,1] -> lane 1, final[1,2] -> lane 5, final[7,2] -> lane 23
    if (l == 1)  out[0] = state;
    if (l == 5)  out[1] = state;
    if (l == 23) out[2] = state;
}

extern "C" void kernel_launch(void* const* d_in, const int* in_sizes, int n_in,
                              void* d_out, int out_size, void* d_ws, size_t ws_size,
                              hipStream_t stream) {
    const float* x       = (const float*)d_in[0]; // [2]
    const float* weights = (const float*)d_in[1]; // [9,3,4]
    const float* noise   = (const float*)d_in[2]; // [130,9,3,4]
    float* out = (float*)d_out;                   // [3] float32
    one_layer_net_kernel<<<1, 1024, 0, stream>>>(x, weights, noise, out);
}